// Round 3
// baseline (157.897 us; speedup 1.0000x reference)
//
#include <hip/hip_runtime.h>
#include <hip/hip_bf16.h>
#include <math.h>

#define BB 4
#define NN 512
#define TT 24
#define NXF 8
#define HH 64
#define PRED 12

typedef __attribute__((ext_vector_type(8))) short short8;
typedef __attribute__((ext_vector_type(4))) float f32x4;
typedef unsigned short ushort;

// ---- workspace layout (float offsets) ----
#define WS_H1THI  0         // 65536 f32 slots = 131072 u16  (H1^T hi plane [b][h][n])
#define WS_H1TLO  65536
#define WS_H2THI  131072
#define WS_H2TLO  196608
#define WS_HL     262144    // 131072  lstm final h (f32)
#define WS_EL     393216    // 2048
#define WS_ER     395264
#define WS_EL2    397312
#define WS_ER2    399360
#define WS_MASK   401408    // 8192 u32 (N x N bitmask, [n][16 words])
#define WS_CTR    409600    // 64 u32 counters

__device__ inline float sigm(float x){ return 1.f/(1.f+__expf(-x)); }
__device__ inline float tanh_fast(float x){ float e=__expf(2.f*x); return 1.f - 2.f/(e+1.f); }
__device__ inline float gelu_exact(float x){ return 0.5f*x*(1.f+erff(x*0.70710678118654752440f)); }
__device__ inline ushort f2bu(float f){           // RNE f32 -> bf16 bits
    unsigned b=__float_as_uint(f);
    return (ushort)((b + 0x7FFFu + ((b>>16)&1u))>>16);
}
__device__ inline float bu2f(ushort u){ return __uint_as_float(((unsigned)u)<<16); }

__device__ inline void fence_arrive(unsigned* c){ __threadfence(); atomicAdd(c, 1u); }
__device__ inline void wait_count(unsigned* c, unsigned tgt){
    while (__hip_atomic_load(c, __ATOMIC_RELAXED, __HIP_MEMORY_SCOPE_AGENT) < tgt)
        __builtin_amdgcn_s_sleep(2);
    __threadfence();
}
__device__ inline void grid_bar(unsigned* c, unsigned tgt){
    __syncthreads();
    if (threadIdx.x == 0){ fence_arrive(c); wait_count(c, tgt); }
    __syncthreads();
}

__global__ void init_ctr_kernel(unsigned* c){ c[threadIdx.x] = 0u; }

// =============== single persistent fused kernel ===============
// blocks 0..127   : GAT pipeline (phase A: H1 pre; B: attn1+GAT2pre; C: attn2+LN+decode)
// blocks 128..255 : LSTM (self-contained precomp, starts immediately)
// block 256       : adjacency mask build
#define LHS 72
#define LXS 40
__global__ __launch_bounds__(256,2) void fused_kernel(
    const float* __restrict__ x, const int* __restrict__ ei, int E,
    const float* __restrict__ Wfc, const float* __restrict__ bfc,
    const float* __restrict__ W1, const float* __restrict__ al1, const float* __restrict__ ar1,
    const float* __restrict__ bias1,
    const float* __restrict__ W2, const float* __restrict__ al2, const float* __restrict__ ar2,
    const float* __restrict__ bias2,
    const float* __restrict__ Wih, const float* __restrict__ Whh,
    const float* __restrict__ bih, const float* __restrict__ bhh,
    const float* __restrict__ g_l, const float* __restrict__ b_l,
    const float* __restrict__ g_g, const float* __restrict__ b_g,
    const float* __restrict__ W_d, const float* __restrict__ b_d,
    ushort* __restrict__ H1Thi, ushort* __restrict__ H1Tlo,
    ushort* __restrict__ H2Thi, ushort* __restrict__ H2Tlo,
    float* __restrict__ hl,
    float* __restrict__ elG, float* __restrict__ erG,
    float* __restrict__ el2G, float* __restrict__ er2G,
    unsigned* __restrict__ maskG, unsigned* __restrict__ ctr,
    float* __restrict__ out)
{
    __shared__ __align__(16) char smem[49152];
    const int t = threadIdx.x;
    const int lane = t & 63;
    const int w = t >> 6;
    const int quad = lane >> 4;
    const int c16 = lane & 15;
    const int blk = blockIdx.x;

    if (blk == 256){
        // ---- mask build ----
        unsigned* msk = (unsigned*)smem;
        for (int i = t; i < 8192; i += 256) msk[i] = 0u;
        __syncthreads();
        for (int e = t; e < E; e += 256){
            int s = ei[e];
            int d = ei[E + e];
            atomicOr(&msk[s*16 + (d>>5)], 1u << (d & 31));
        }
        __syncthreads();
        for (int i = t; i < 8192; i += 256) maskG[i] = msk[i];
        __syncthreads();
        if (t == 0) fence_arrive(ctr + 0);
        return;
    }

    if (blk >= 128){
        // ---------------- LSTM branch: starts immediately, self-contained precomp ----------------
        const int m0 = (blk - 128) * 16;
        float* sWfcL = (float*)smem;            // 2048
        float* sbfc  = (float*)(smem + 2048);   // 256
        sWfcL[t] = Wfc[t]; sWfcL[t+256] = Wfc[t+256];
        if (t < 64) sbfc[t] = bfc[t];
        __syncthreads();

        short8 bw[4][2]; short8 bx[4]; float bc[4];
        #pragma unroll
        for (int tt = 0; tt < 4; ++tt){
            const int ng = (w + 4*tt)*16 + c16;
            #pragma unroll
            for (int ks = 0; ks < 2; ++ks){
                const float* wp = Whh + (size_t)ng*64 + ks*32 + quad*8;   // direct global read (Whh is 64KB, L2-resident)
                short8 v;
                #pragma unroll
                for (int j = 0; j < 8; ++j) v[j] = (short)f2bu(wp[j]);
                bw[tt][ks] = v;
            }
        }
        {   // wcomb (Wfc^T row-combined into Wih) + bcomb, lane (quad,c16) computes tt=quad
            const int myng = (w + 4*quad)*16 + c16;
            float accj[8] = {0,0,0,0,0,0,0,0};
            float accb = 0.f;
            const float4* wr4 = (const float4*)(Wih + (size_t)myng*64);
            #pragma unroll
            for (int k4 = 0; k4 < 16; ++k4){
                float4 wv = wr4[k4];
                accb += sbfc[4*k4+0]*wv.x; accb += sbfc[4*k4+1]*wv.y;
                accb += sbfc[4*k4+2]*wv.z; accb += sbfc[4*k4+3]*wv.w;
                #pragma unroll
                for (int j = 0; j < 8; ++j){
                    accj[j] += sWfcL[j*64+4*k4+0]*wv.x;
                    accj[j] += sWfcL[j*64+4*k4+1]*wv.y;
                    accj[j] += sWfcL[j*64+4*k4+2]*wv.z;
                    accj[j] += sWfcL[j*64+4*k4+3]*wv.w;
                }
            }
            accb += bih[myng] + bhh[myng];
            #pragma unroll
            for (int tt = 0; tt < 4; ++tt){
                bc[tt] = __shfl(accb, tt*16 + c16);
                short8 vx = {0,0,0,0,0,0,0,0};
                #pragma unroll
                for (int j = 0; j < 8; ++j){
                    float wv = __shfl(accj[j], tt*16 + c16);
                    if (quad == 0) vx[j] = (short)f2bu(wv);
                }
                bx[tt] = vx;
            }
        }
        __syncthreads();   // done reading sWfcL/sbfc region

        ushort* hbi = (ushort*)smem;            // [2][16*LHS]
        ushort* hlo = (ushort*)(smem + 4608);
        ushort* xls = (ushort*)(smem + 9216);   // [TT*16*LXS]
        {
            unsigned* h0 = (unsigned*)hbi;
            unsigned* l0 = (unsigned*)hlo;
            for (int i = t; i < 2*16*LHS/2; i += 256){ h0[i] = 0u; l0[i] = 0u; }
            unsigned* xw = (unsigned*)xls;
            for (int i = t; i < TT*16*LXS/2; i += 256) xw[i] = 0u;
        }
        __syncthreads();
        for (int i = t; i < 16*TT*NXF; i += 256){
            int r = i / (TT*NXF);
            int rem = i - r*(TT*NXF);
            int st = rem >> 3, f = rem & 7;
            xls[st*(16*LXS) + r*LXS + f] = f2bu(x[(size_t)(m0+r)*(TT*NXF) + rem]);
        }
        __syncthreads();

        float cst[4] = {0,0,0,0};
        float hf[4]  = {0,0,0,0};

        for (int st = 0; st < TT; ++st){
            const int p = st & 1;
            const ushort* hb  = hbi + p*(16*LHS);
            const ushort* hl_ = hlo + p*(16*LHS);
            short8 ahi0 = *(const short8*)&hb[c16*LHS + quad*8];
            short8 ahi1 = *(const short8*)&hb[c16*LHS + 32 + quad*8];
            short8 alo0 = *(const short8*)&hl_[c16*LHS + quad*8];
            short8 alo1 = *(const short8*)&hl_[c16*LHS + 32 + quad*8];
            short8 ax   = *(const short8*)&xls[st*(16*LXS) + c16*LXS + quad*8];
            f32x4 acc[4];
            #pragma unroll
            for (int tt = 0; tt < 4; ++tt){
                f32x4 a = {bc[tt], bc[tt], bc[tt], bc[tt]};
                a = __builtin_amdgcn_mfma_f32_16x16x32_bf16(ax,   bx[tt],    a, 0,0,0);
                a = __builtin_amdgcn_mfma_f32_16x16x32_bf16(ahi0, bw[tt][0], a, 0,0,0);
                a = __builtin_amdgcn_mfma_f32_16x16x32_bf16(ahi1, bw[tt][1], a, 0,0,0);
                a = __builtin_amdgcn_mfma_f32_16x16x32_bf16(alo0, bw[tt][0], a, 0,0,0);
                a = __builtin_amdgcn_mfma_f32_16x16x32_bf16(alo1, bw[tt][1], a, 0,0,0);
                acc[tt] = a;
            }
            ushort* ho   = hbi + (p^1)*(16*LHS);
            ushort* lo_o = hlo + (p^1)*(16*LHS);
            #pragma unroll
            for (int reg = 0; reg < 4; ++reg){
                float gi = acc[0][reg], gf = acc[1][reg], gg = acc[2][reg], go = acc[3][reg];
                float cn = sigm(gf)*cst[reg] + sigm(gi)*tanh_fast(gg);
                cst[reg] = cn;
                float hn = sigm(go)*tanh_fast(cn);
                hf[reg] = hn;
                ushort hu = f2bu(hn);
                float lov = hn - bu2f(hu);
                int addr = (quad*4+reg)*LHS + w*16 + c16;
                ho[addr] = hu;
                lo_o[addr] = f2bu(lov);
            }
            __syncthreads();
        }
        #pragma unroll
        for (int reg = 0; reg < 4; ++reg)
            hl[(size_t)(m0 + quad*4 + reg)*HH + w*16 + c16] = hf[reg];
        __syncthreads();
        if (t == 0) fence_arrive(ctr + 32);   // lstm_done
        return;
    }

    // ================= GAT pipeline blocks (0..127) =================
    const int b   = blk >> 5;
    const int m0l = (blk & 31) * 16;
    const int m0g = blk * 16;

    // ---------------- phase A: H1 = (x_last@Wfc+bfc)@W1, el/er, H1^T hi/lo ----------------
    {
        float* sw1  = (float*)smem;                       // 16384
        float* swfc = (float*)(smem + 16384);             // 2048
        float* sb   = (float*)(smem + 18432);             // 256
        float* sal  = (float*)(smem + 18688);
        float* sar  = (float*)(smem + 18944);
        float (*sx)[NXF] = (float(*)[NXF])(smem + 19200); // 512
        float (*sxh)[68] = (float(*)[68])(smem + 19712);  // 4352 -> 24064
        ushort (*thi)[68] = (ushort(*)[68])(smem + 24064);// 2176
        ushort (*tlo)[68] = (ushort(*)[68])(smem + 26240);// 2176 -> 28416

        #pragma unroll
        for (int i = 0; i < 16; ++i) sw1[t + 256*i] = W1[t + 256*i];
        swfc[t] = Wfc[t];
        swfc[t+256] = Wfc[t+256];
        if (t < 64) sb[t] = bfc[t];
        else if (t < 128) sal[t-64] = al1[t-64];
        else if (t < 192) sar[t-128] = ar1[t-128];
        if (t < 128){
            int rr = t >> 3, f = t & 7;
            sx[rr][f] = x[(size_t)(m0g + rr)*(TT*NXF) + (TT-1)*NXF + f];
        }
        __syncthreads();
        #pragma unroll
        for (int rr = 0; rr < 4; ++rr){
            const int row = w*4 + rr;
            float v = sb[lane];
            #pragma unroll
            for (int f = 0; f < NXF; ++f) v += sx[row][f]*swfc[f*HH + lane];
            sxh[row][lane] = v;
        }
        __syncthreads();
        #pragma unroll
        for (int rr = 0; rr < 4; ++rr){
            const int row = w*4 + rr;
            float acc = 0.f;
            const float4* xr = (const float4*)&sxh[row][0];
            #pragma unroll
            for (int k4 = 0; k4 < 16; ++k4){
                float4 xv = xr[k4];
                acc += xv.x*sw1[(4*k4+0)*HH+lane] + xv.y*sw1[(4*k4+1)*HH+lane]
                     + xv.z*sw1[(4*k4+2)*HH+lane] + xv.w*sw1[(4*k4+3)*HH+lane];
            }
            ushort hh = f2bu(acc);
            thi[row][lane] = hh;
            tlo[row][lane] = f2bu(acc - bu2f(hh));
            float v1 = acc*sal[lane], v2 = acc*sar[lane];
            #pragma unroll
            for (int o = 32; o; o >>= 1){ v1 += __shfl_xor(v1,o); v2 += __shfl_xor(v2,o); }
            if (lane == 0){ elG[m0g + row] = v1; erG[m0g + row] = v2; }
        }
        __syncthreads();
        #pragma unroll
        for (int p = 0; p < 4; ++p){
            int hh2 = (t >> 4) + 16*p, n2 = t & 15;
            size_t og = ((size_t)b*HH + hh2)*NN + m0l + n2;
            H1Thi[og] = thi[n2][hh2];
            H1Tlo[og] = tlo[n2][hh2];
        }
    }
    grid_bar(ctr + 0, 129);   // all GAT phase A done + mask built

    // ---------------- phase B: attn layer1 + GAT2-pre ----------------
    {
        unsigned (*smask)[16] = (unsigned(*)[16])smem;                 // 1024
        float* er_s  = (float*)(smem + 1024);                          // 2048
        float* sal   = (float*)(smem + 3072);                          // 256
        float* sar   = (float*)(smem + 3328);                          // 256
        ushort (*ahi)[520] = (ushort(*)[520])(smem + 3584);            // 16640
        ushort (*alo_)[520] = (ushort(*)[520])(smem + 20224);          // 16640 -> 36864
        float (*xh2)[68] = (float(*)[68])(smem + 36864);               // 4352 -> 41216
        ushort (*th2)[68] = (ushort(*)[68])(smem + 41216);             // 2176
        ushort (*tl2)[68] = (ushort(*)[68])(smem + 43392);             // 2176 -> 45568
        float* sw2 = (float*)(smem + 3584);                            // overlay alpha after MFMA
        const int l = lane;

        if (t < 64) sal[t] = al2[t]; else if (t < 128) sar[t-64] = ar2[t-64];
        ((unsigned*)smask)[t] = maskG[m0l*16 + t];
        er_s[t] = erG[b*NN + t];
        er_s[t+256] = erG[b*NN + t + 256];
        __syncthreads();
        for (int q = 0; q < 4; ++q){
            const int i = w*4 + q;
            const float elv = elG[b*NN + m0l + i];
            float e8[8]; unsigned mk = 0; float mx = -1e30f;
            #pragma unroll
            for (int j = 0; j < 8; ++j){
                int n = l + 64*j;
                float ev = elv + er_s[n];
                ev = ev >= 0.f ? ev : 0.2f*ev;
                unsigned mb = (smask[i][(l>>5) + 2*j] >> (l & 31)) & 1u;
                e8[j] = ev;
                if (mb){ mk |= (1u<<j); mx = fmaxf(mx, ev); }
            }
            #pragma unroll
            for (int o = 32; o; o >>= 1) mx = fmaxf(mx, __shfl_xor(mx, o));
            float s = 0.f;
            #pragma unroll
            for (int j = 0; j < 8; ++j){
                float p = ((mk>>j) & 1u) ? __expf(e8[j]-mx) : 0.f;
                e8[j] = p; s += p;
            }
            #pragma unroll
            for (int o = 32; o; o >>= 1) s += __shfl_xor(s, o);
            const float inv = 1.f/s;
            #pragma unroll
            for (int j = 0; j < 8; ++j){
                float p = e8[j]*inv;
                ushort ph = f2bu(p);
                ahi[i][l + 64*j] = ph;
                alo_[i][l + 64*j] = f2bu(p - bu2f(ph));
            }
        }
        __syncthreads();

        f32x4 acc = {0.f,0.f,0.f,0.f};
        {
            const ushort* bhiP = H1Thi + ((size_t)b*HH + w*16 + c16)*NN + quad*8;
            const ushort* bloP = H1Tlo + ((size_t)b*HH + w*16 + c16)*NN + quad*8;
            const ushort* ahiP = &ahi[c16][quad*8];
            const ushort* aloP = &alo_[c16][quad*8];
            #pragma unroll
            for (int kk = 0; kk < 16; ++kk){
                short8 fa_hi = *(const short8*)(ahiP + kk*32);
                short8 fa_lo = *(const short8*)(aloP + kk*32);
                short8 fb_hi = *(const short8*)(bhiP + kk*32);
                short8 fb_lo = *(const short8*)(bloP + kk*32);
                acc = __builtin_amdgcn_mfma_f32_16x16x32_bf16(fa_hi, fb_hi, acc, 0,0,0);
                acc = __builtin_amdgcn_mfma_f32_16x16x32_bf16(fa_lo, fb_hi, acc, 0,0,0);
                acc = __builtin_amdgcn_mfma_f32_16x16x32_bf16(fa_hi, fb_lo, acc, 0,0,0);
            }
        }
        {
            const int h = w*16 + c16;
            const float bv = bias1[h];
            #pragma unroll
            for (int reg = 0; reg < 4; ++reg)
                xh2[quad*4 + reg][h] = gelu_exact(acc[reg] + bv);
        }
        __syncthreads();
        #pragma unroll
        for (int i = 0; i < 16; ++i) sw2[t + 256*i] = W2[t + 256*i];
        __syncthreads();
        {
            const int h = l;
            for (int q = 0; q < 4; ++q){
                const int i = w + 4*q;
                float acc2 = 0.f;
                const float4* xr = (const float4*)&xh2[i][0];
                #pragma unroll
                for (int k4 = 0; k4 < 16; ++k4){
                    float4 xv = xr[k4];
                    acc2 += xv.x*sw2[(4*k4+0)*HH+h] + xv.y*sw2[(4*k4+1)*HH+h]
                          + xv.z*sw2[(4*k4+2)*HH+h] + xv.w*sw2[(4*k4+3)*HH+h];
                }
                ushort vh = f2bu(acc2);
                th2[i][h] = vh;
                tl2[i][h] = f2bu(acc2 - bu2f(vh));
                float v1 = acc2*sal[h], v2 = acc2*sar[h];
                #pragma unroll
                for (int o = 32; o; o >>= 1){ v1 += __shfl_xor(v1,o); v2 += __shfl_xor(v2,o); }
                if (h == 0){ el2G[b*NN + m0l + i] = v1; er2G[b*NN + m0l + i] = v2; }
            }
        }
        __syncthreads();
        #pragma unroll
        for (int p = 0; p < 4; ++p){
            int hh2 = (t >> 4) + 16*p, n2 = t & 15;
            size_t og = ((size_t)b*HH + hh2)*NN + m0l + n2;
            H2Thi[og] = th2[n2][hh2];
            H2Tlo[og] = tl2[n2][hh2];
        }
    }
    grid_bar(ctr + 16, 128);   // all GAT phase B done

    // ---------------- phase C: attn layer2 + LN(g2)+LN(hl) + decode ----------------
    {
        unsigned (*smask)[16] = (unsigned(*)[16])smem;                 // 1024
        float* er_s  = (float*)(smem + 1024);                          // 2048
        ushort (*ahi)[520] = (ushort(*)[520])(smem + 3072);            // -> 19712
        ushort (*alo_)[520] = (ushort(*)[520])(smem + 19712);          // -> 36352
        float* sg2  = (float*)(smem + 36352);                          // 4096 -> 40448
        float* sdec = (float*)(smem + 3072);                           // overlay alpha
        const int l = lane;

        ((unsigned*)smask)[t] = maskG[m0l*16 + t];
        er_s[t] = er2G[b*NN + t];
        er_s[t+256] = er2G[b*NN + t + 256];
        __syncthreads();
        for (int q = 0; q < 4; ++q){
            const int i = w*4 + q;
            const float elv = el2G[b*NN + m0l + i];
            float e8[8]; unsigned mk = 0; float mx = -1e30f;
            #pragma unroll
            for (int j = 0; j < 8; ++j){
                int n = l + 64*j;
                float ev = elv + er_s[n];
                ev = ev >= 0.f ? ev : 0.2f*ev;
                unsigned mb = (smask[i][(l>>5) + 2*j] >> (l & 31)) & 1u;
                e8[j] = ev;
                if (mb){ mk |= (1u<<j); mx = fmaxf(mx, ev); }
            }
            #pragma unroll
            for (int o = 32; o; o >>= 1) mx = fmaxf(mx, __shfl_xor(mx, o));
            float s = 0.f;
            #pragma unroll
            for (int j = 0; j < 8; ++j){
                float p = ((mk>>j) & 1u) ? __expf(e8[j]-mx) : 0.f;
                e8[j] = p; s += p;
            }
            #pragma unroll
            for (int o = 32; o; o >>= 1) s += __shfl_xor(s, o);
            const float inv = 1.f/s;
            #pragma unroll
            for (int j = 0; j < 8; ++j){
                float p = e8[j]*inv;
                ushort ph = f2bu(p);
                ahi[i][l + 64*j] = ph;
                alo_[i][l + 64*j] = f2bu(p - bu2f(ph));
            }
        }
        __syncthreads();

        f32x4 acc = {0.f,0.f,0.f,0.f};
        {
            const ushort* bhiP = H2Thi + ((size_t)b*HH + w*16 + c16)*NN + quad*8;
            const ushort* bloP = H2Tlo + ((size_t)b*HH + w*16 + c16)*NN + quad*8;
            const ushort* ahiP = &ahi[c16][quad*8];
            const ushort* aloP = &alo_[c16][quad*8];
            #pragma unroll
            for (int kk = 0; kk < 16; ++kk){
                short8 fa_hi = *(const short8*)(ahiP + kk*32);
                short8 fa_lo = *(const short8*)(aloP + kk*32);
                short8 fb_hi = *(const short8*)(bhiP + kk*32);
                short8 fb_lo = *(const short8*)(bloP + kk*32);
                acc = __builtin_amdgcn_mfma_f32_16x16x32_bf16(fa_hi, fb_hi, acc, 0,0,0);
                acc = __builtin_amdgcn_mfma_f32_16x16x32_bf16(fa_lo, fb_hi, acc, 0,0,0);
                acc = __builtin_amdgcn_mfma_f32_16x16x32_bf16(fa_hi, fb_lo, acc, 0,0,0);
            }
        }
        {
            const int h = w*16 + c16;
            const float bv = bias2[h];
            #pragma unroll
            for (int reg = 0; reg < 4; ++reg)
                sg2[(quad*4 + reg)*HH + h] = gelu_exact(acc[reg] + bv);
        }
        __syncthreads();
        if (t == 0) wait_count(ctr + 32, 128);   // LSTM complete
        __syncthreads();
        const int gbase = b*NN + m0l;
        {
            const int h = l;
            for (int q = 0; q < 4; ++q){
                const int ml = w*4 + q;
                float gv = sg2[ml*HH + h];
                float lv = hl[(size_t)(gbase + ml)*HH + h];

                float s1 = gv;
                #pragma unroll
                for (int o = 32; o; o >>= 1) s1 += __shfl_xor(s1, o);
                float dg = gv - s1*(1.f/64.f);
                float v1 = dg*dg;
                #pragma unroll
                for (int o = 32; o; o >>= 1) v1 += __shfl_xor(v1, o);
                float lng = dg*rsqrtf(v1*(1.f/64.f) + 1e-5f)*g_g[h] + b_g[h];

                float s2 = lv;
                #pragma unroll
                for (int o = 32; o; o >>= 1) s2 += __shfl_xor(s2, o);
                float dl = lv - s2*(1.f/64.f);
                float v2 = dl*dl;
                #pragma unroll
                for (int o = 32; o; o >>= 1) v2 += __shfl_xor(v2, o);
                float lnl = dl*rsqrtf(v2*(1.f/64.f) + 1e-5f)*g_l[h] + b_l[h];

                sdec[ml*HH + h] = lng + lnl;
            }
        }
        __syncthreads();
        if (t < 16*PRED){
            int rr = t / PRED, pp = t - rr*PRED;
            float a = b_d[pp];
            #pragma unroll
            for (int k = 0; k < HH; ++k) a += sdec[rr*HH + k]*W_d[k*PRED + pp];
            out[(size_t)(gbase + rr)*PRED + pp] = a;
        }
    }
}

extern "C" void kernel_launch(void* const* d_in, const int* in_sizes, int n_in,
                              void* d_out, int out_size, void* d_ws, size_t ws_size,
                              hipStream_t stream){
    const float* x    = (const float*)d_in[0];
    const int*   ei   = (const int*)  d_in[1];
    const float* Wfc  = (const float*)d_in[2];
    const float* bfc  = (const float*)d_in[3];
    const float* W1   = (const float*)d_in[4];
    const float* al1  = (const float*)d_in[5];
    const float* ar1  = (const float*)d_in[6];
    const float* bias1= (const float*)d_in[7];
    const float* W2   = (const float*)d_in[8];
    const float* al2  = (const float*)d_in[9];
    const float* ar2  = (const float*)d_in[10];
    const float* bias2= (const float*)d_in[11];
    const float* Wih  = (const float*)d_in[12];
    const float* Whh  = (const float*)d_in[13];
    const float* bih  = (const float*)d_in[14];
    const float* bhh  = (const float*)d_in[15];
    const float* g_l  = (const float*)d_in[16];
    const float* b_l  = (const float*)d_in[17];
    const float* g_g  = (const float*)d_in[18];
    const float* b_g  = (const float*)d_in[19];
    const float* W_d  = (const float*)d_in[20];
    const float* b_d  = (const float*)d_in[21];

    float* ws = (float*)d_ws;
    const int E = in_sizes[1] / 2;
    unsigned* ctr = (unsigned*)(ws + WS_CTR);

    init_ctr_kernel<<<1, 64, 0, stream>>>(ctr);
    fused_kernel<<<257, 256, 0, stream>>>(
        x, ei, E, Wfc, bfc, W1, al1, ar1, bias1, W2, al2, ar2, bias2,
        Wih, Whh, bih, bhh, g_l, b_l, g_g, b_g, W_d, b_d,
        (ushort*)(ws+WS_H1THI), (ushort*)(ws+WS_H1TLO),
        (ushort*)(ws+WS_H2THI), (ushort*)(ws+WS_H2TLO),
        ws+WS_HL,
        ws+WS_EL, ws+WS_ER, ws+WS_EL2, ws+WS_ER2,
        (unsigned*)(ws+WS_MASK), ctr,
        (float*)d_out);
}

// Round 4
// 151.729 us; speedup vs baseline: 1.0407x; 1.0407x over previous
//
#include <hip/hip_runtime.h>
#include <hip/hip_bf16.h>
#include <math.h>

#define BB 4
#define NN 512
#define TT 24
#define NXF 8
#define HH 64
#define PRED 12

typedef __attribute__((ext_vector_type(8))) short short8;
typedef __attribute__((ext_vector_type(4))) float f32x4;
typedef unsigned short ushort;

// ---- workspace layout (float offsets) ----
#define WS_H1THI  0         // 65536 f32 slots = 131072 u16  (H1^T hi plane [b][h][n])
#define WS_H1TLO  65536
#define WS_H2THI  131072
#define WS_H2TLO  196608
#define WS_HL     262144    // 131072  lstm final h (f32)
#define WS_EL     393216    // 2048
#define WS_ER     395264
#define WS_EL2    397312
#define WS_ER2    399360
#define WS_WCOMB  401408    // 2048 f32
#define WS_BCOMB  403456    // 256 f32
#define WS_WHHFRAG 403712   // 16384 bf16 (= 8192 f32 slots)
#define WS_MASK   411904    // 8192 u32 (N x N bitmask, [n][16 words])

__device__ inline float sigm(float x){ return 1.f/(1.f+__expf(-x)); }
__device__ inline float tanh_fast(float x){ float e=__expf(2.f*x); return 1.f - 2.f/(e+1.f); }
__device__ inline float gelu_exact(float x){ return 0.5f*x*(1.f+erff(x*0.70710678118654752440f)); }
__device__ inline ushort f2bu(float f){           // RNE f32 -> bf16 bits
    unsigned b=__float_as_uint(f);
    return (ushort)((b + 0x7FFFu + ((b>>16)&1u))>>16);
}
__device__ inline float bu2f(ushort u){ return __uint_as_float(((unsigned)u)<<16); }

// =============== K1: blocks 0-127: H1(16 rows/blk) -> H1^T hi/lo + el/er
//                    blocks 128-135: LSTM precomp (wcomb/bcomb/whhfrag)
//                    block 136: adjacency mask build ===============
__global__ __launch_bounds__(256,2) void gat1pre_kernel(
    const float* __restrict__ x, const float* __restrict__ Wfc, const float* __restrict__ bfc,
    const float* __restrict__ W1, const float* __restrict__ al1, const float* __restrict__ ar1,
    const float* __restrict__ Wih, const float* __restrict__ Whh,
    const float* __restrict__ bih, const float* __restrict__ bhh,
    const int* __restrict__ ei, int E,
    ushort* __restrict__ H1Thi, ushort* __restrict__ H1Tlo,
    float* __restrict__ elG, float* __restrict__ erG,
    float* __restrict__ wcombG, float* __restrict__ bcombG,
    ushort* __restrict__ whhfrag, unsigned* __restrict__ maskG)
{
    __shared__ __align__(16) char smem[32768];
    const int t = threadIdx.x;
    const int blk = blockIdx.x;

    if (blk == 136){
        // ---- mask build (verified round 1/3) ----
        unsigned* msk = (unsigned*)smem;
        for (int i = t; i < 8192; i += 256) msk[i] = 0u;
        __syncthreads();
        for (int e = t; e < E; e += 256){
            int s = ei[e];
            int d = ei[E + e];
            atomicOr(&msk[s*16 + (d>>5)], 1u << (d & 31));
        }
        __syncthreads();
        for (int i = t; i < 8192; i += 256) maskG[i] = msk[i];
        return;
    }

    if (blk >= 128){
        // ---- LSTM precomp (verified round 1) ----
        const int f = blk - 128;   // 0..7
        const int ng = t;
        float accf = 0.f, accb = 0.f;
        const float* wr = Wih + ng*64;
        #pragma unroll
        for (int k = 0; k < 64; ++k){
            float wv = wr[k];
            accf += Wfc[f*64 + k] * wv;
            accb += bfc[k] * wv;
        }
        wcombG[f*256 + ng] = accf;
        if (f == 0) bcombG[ng] = accb + bih[ng] + bhh[ng];
        #pragma unroll
        for (int u = 0; u < 8; ++u){
            int o = f*2048 + u*256 + t;
            int F  = o >> 9;
            int ln = (o >> 3) & 63;
            int j  = o & 7;
            int w_ = F >> 3, tt = (F >> 1) & 3, ks = F & 1;
            int q = ln >> 4, c = ln & 15;
            int ngx = (w_ + 4*tt)*16 + c;
            whhfrag[o] = f2bu(Whh[ngx*64 + ks*32 + q*8 + j]);
        }
        return;
    }

    // ---- GAT phase A: 16 rows per block (verified round 3 fused phase A) ----
    const int lane = t & 63;
    const int w = t >> 6;
    const int b   = blk >> 5;
    const int m0l = (blk & 31) * 16;
    const int m0g = blk * 16;

    float* sw1  = (float*)smem;                       // 16384
    float* swfc = (float*)(smem + 16384);             // 2048
    float* sb   = (float*)(smem + 18432);             // 256
    float* sal  = (float*)(smem + 18688);
    float* sar  = (float*)(smem + 18944);
    float (*sx)[NXF] = (float(*)[NXF])(smem + 19200); // 512
    float (*sxh)[68] = (float(*)[68])(smem + 19712);  // 4352 -> 24064
    ushort (*thi)[68] = (ushort(*)[68])(smem + 24064);// 2176
    ushort (*tlo)[68] = (ushort(*)[68])(smem + 26240);// 2176 -> 28416

    #pragma unroll
    for (int i = 0; i < 16; ++i) sw1[t + 256*i] = W1[t + 256*i];
    swfc[t] = Wfc[t];
    swfc[t+256] = Wfc[t+256];
    if (t < 64) sb[t] = bfc[t];
    else if (t < 128) sal[t-64] = al1[t-64];
    else if (t < 192) sar[t-128] = ar1[t-128];
    if (t < 128){
        int rr = t >> 3, f = t & 7;
        sx[rr][f] = x[(size_t)(m0g + rr)*(TT*NXF) + (TT-1)*NXF + f];
    }
    __syncthreads();
    #pragma unroll
    for (int rr = 0; rr < 4; ++rr){
        const int row = w*4 + rr;
        float v = sb[lane];
        #pragma unroll
        for (int f = 0; f < NXF; ++f) v += sx[row][f]*swfc[f*HH + lane];
        sxh[row][lane] = v;
    }
    __syncthreads();
    #pragma unroll
    for (int rr = 0; rr < 4; ++rr){
        const int row = w*4 + rr;
        float acc = 0.f;
        const float4* xr = (const float4*)&sxh[row][0];
        #pragma unroll
        for (int k4 = 0; k4 < 16; ++k4){
            float4 xv = xr[k4];
            acc += xv.x*sw1[(4*k4+0)*HH+lane] + xv.y*sw1[(4*k4+1)*HH+lane]
                 + xv.z*sw1[(4*k4+2)*HH+lane] + xv.w*sw1[(4*k4+3)*HH+lane];
        }
        ushort hh = f2bu(acc);
        thi[row][lane] = hh;
        tlo[row][lane] = f2bu(acc - bu2f(hh));
        float v1 = acc*sal[lane], v2 = acc*sar[lane];
        #pragma unroll
        for (int o = 32; o; o >>= 1){ v1 += __shfl_xor(v1,o); v2 += __shfl_xor(v2,o); }
        if (lane == 0){ elG[m0g + row] = v1; erG[m0g + row] = v2; }
    }
    __syncthreads();
    #pragma unroll
    for (int p = 0; p < 4; ++p){
        int hh2 = (t >> 4) + 16*p, n2 = t & 15;
        size_t og = ((size_t)b*HH + hh2)*NN + m0l + n2;
        H1Thi[og] = thi[n2][hh2];
        H1Tlo[og] = tlo[n2][hh2];
    }
}

// =============== K2: blocks 0-127 = attn layer1 + GAT2-pre ; blocks 128-255 = LSTM -> hl ===============
#define LHS 72
#define LXS 40
__global__ __launch_bounds__(256,2) void mid_fused_kernel(
    const ushort* __restrict__ H1Thi, const ushort* __restrict__ H1Tlo,
    const float* __restrict__ el_in, const float* __restrict__ er_in,
    const unsigned* __restrict__ maskG,
    const float* __restrict__ bias1,
    const float* __restrict__ W2, const float* __restrict__ al2, const float* __restrict__ ar2,
    ushort* __restrict__ H2Thi, ushort* __restrict__ H2Tlo,
    float* __restrict__ el2, float* __restrict__ er2,
    const float* __restrict__ x,
    const float* __restrict__ wcombG, const float* __restrict__ bcombG,
    const ushort* __restrict__ whhfrag,
    float* __restrict__ hl)
{
    __shared__ __align__(16) char smem[45568];
    const int t = threadIdx.x;
    const int lane = t & 63;
    const int w = t >> 6;
    const int quad = lane >> 4;
    const int c16 = lane & 15;

    if (blockIdx.x >= 128){
        // ---------------- LSTM branch (verified round 1) ----------------
        ushort* hbi = (ushort*)smem;            // [2][16*LHS]
        ushort* hlo = (ushort*)(smem + 4608);
        ushort* xls = (ushort*)(smem + 9216);   // [TT*16*LXS]
        const int m0 = (blockIdx.x - 128) * 16;

        {
            unsigned* h0 = (unsigned*)hbi;
            unsigned* l0 = (unsigned*)hlo;
            for (int i = t; i < 2*16*LHS/2; i += 256){ h0[i] = 0u; l0[i] = 0u; }
            unsigned* xw = (unsigned*)xls;
            for (int i = t; i < TT*16*LXS/2; i += 256) xw[i] = 0u;
        }
        short8 bw[4][2]; short8 bx[4]; float bc[4];
        #pragma unroll
        for (int tt = 0; tt < 4; ++tt){
            const int ng = (w + 4*tt)*16 + c16;
            bc[tt] = bcombG[ng];
            #pragma unroll
            for (int ks = 0; ks < 2; ++ks)
                bw[tt][ks] = *(const short8*)&whhfrag[(((w*4+tt)*2)+ks)*512 + lane*8];
            short8 vx = {0,0,0,0,0,0,0,0};
            if (quad == 0){
                #pragma unroll
                for (int j = 0; j < 8; ++j) vx[j] = (short)f2bu(wcombG[j*256 + ng]);
            }
            bx[tt] = vx;
        }
        __syncthreads();
        for (int i = t; i < 16*TT*NXF; i += 256){
            int r = i / (TT*NXF);
            int rem = i - r*(TT*NXF);
            int st = rem >> 3, f = rem & 7;
            xls[st*(16*LXS) + r*LXS + f] = f2bu(x[(size_t)(m0+r)*(TT*NXF) + rem]);
        }
        __syncthreads();

        float cst[4] = {0,0,0,0};
        float hf[4]  = {0,0,0,0};

        for (int st = 0; st < TT; ++st){
            const int p = st & 1;
            const ushort* hb  = hbi + p*(16*LHS);
            const ushort* hl_ = hlo + p*(16*LHS);
            short8 ahi0 = *(const short8*)&hb[c16*LHS + quad*8];
            short8 ahi1 = *(const short8*)&hb[c16*LHS + 32 + quad*8];
            short8 alo0 = *(const short8*)&hl_[c16*LHS + quad*8];
            short8 alo1 = *(const short8*)&hl_[c16*LHS + 32 + quad*8];
            short8 ax   = *(const short8*)&xls[st*(16*LXS) + c16*LXS + quad*8];
            f32x4 acc[4];
            #pragma unroll
            for (int tt = 0; tt < 4; ++tt){
                f32x4 a = {bc[tt], bc[tt], bc[tt], bc[tt]};
                a = __builtin_amdgcn_mfma_f32_16x16x32_bf16(ax,   bx[tt],    a, 0,0,0);
                a = __builtin_amdgcn_mfma_f32_16x16x32_bf16(ahi0, bw[tt][0], a, 0,0,0);
                a = __builtin_amdgcn_mfma_f32_16x16x32_bf16(ahi1, bw[tt][1], a, 0,0,0);
                a = __builtin_amdgcn_mfma_f32_16x16x32_bf16(alo0, bw[tt][0], a, 0,0,0);
                a = __builtin_amdgcn_mfma_f32_16x16x32_bf16(alo1, bw[tt][1], a, 0,0,0);
                acc[tt] = a;
            }
            ushort* ho   = hbi + (p^1)*(16*LHS);
            ushort* lo_o = hlo + (p^1)*(16*LHS);
            #pragma unroll
            for (int reg = 0; reg < 4; ++reg){
                float gi = acc[0][reg], gf = acc[1][reg], gg = acc[2][reg], go = acc[3][reg];
                float cn = sigm(gf)*cst[reg] + sigm(gi)*tanh_fast(gg);
                cst[reg] = cn;
                float hn = sigm(go)*tanh_fast(cn);
                hf[reg] = hn;
                ushort hu = f2bu(hn);
                float lov = hn - bu2f(hu);
                int addr = (quad*4+reg)*LHS + w*16 + c16;
                ho[addr] = hu;
                lo_o[addr] = f2bu(lov);
            }
            __syncthreads();
        }
        #pragma unroll
        for (int reg = 0; reg < 4; ++reg)
            hl[(size_t)(m0 + quad*4 + reg)*HH + w*16 + c16] = hf[reg];
        return;
    }

    // ---------------- attn layer1 + GAT2-pre branch ----------------
    unsigned (*smask)[16] = (unsigned(*)[16])smem;                 // 1024
    float* er_s  = (float*)(smem + 1024);                          // 2048
    float* sal   = (float*)(smem + 3072);                          // 256
    float* sar   = (float*)(smem + 3328);                          // 256
    ushort (*ahi)[520] = (ushort(*)[520])(smem + 3584);            // 16640
    ushort (*alo_)[520] = (ushort(*)[520])(smem + 20224);          // 16640 -> 36864
    float (*xh2)[68] = (float(*)[68])(smem + 36864);               // 4352 -> 41216
    ushort (*th2)[68] = (ushort(*)[68])(smem + 41216);             // 2176
    ushort (*tl2)[68] = (ushort(*)[68])(smem + 43392);             // 2176 -> 45568
    float* sw2 = (float*)(smem + 3584);                            // overlay alpha after MFMA

    const int b = blockIdx.x >> 5;
    const int m0 = (blockIdx.x & 31) * 16;
    const int l = lane;

    if (t < 64) sal[t] = al2[t]; else if (t < 128) sar[t-64] = ar2[t-64];
    ((unsigned*)smask)[t] = maskG[m0*16 + t];
    er_s[t] = er_in[b*NN + t];
    er_s[t+256] = er_in[b*NN + t + 256];
    __syncthreads();
    for (int q = 0; q < 4; ++q){
        const int i = w*4 + q;
        const float elv = el_in[b*NN + m0 + i];
        float e8[8]; unsigned mk = 0; float mx = -1e30f;
        #pragma unroll
        for (int j = 0; j < 8; ++j){
            int n = l + 64*j;
            float ev = elv + er_s[n];
            ev = ev >= 0.f ? ev : 0.2f*ev;
            unsigned mb = (smask[i][(l>>5) + 2*j] >> (l & 31)) & 1u;
            e8[j] = ev;
            if (mb){ mk |= (1u<<j); mx = fmaxf(mx, ev); }
        }
        #pragma unroll
        for (int o = 32; o; o >>= 1) mx = fmaxf(mx, __shfl_xor(mx, o));
        float s = 0.f;
        #pragma unroll
        for (int j = 0; j < 8; ++j){
            float p = ((mk>>j) & 1u) ? __expf(e8[j]-mx) : 0.f;
            e8[j] = p; s += p;
        }
        #pragma unroll
        for (int o = 32; o; o >>= 1) s += __shfl_xor(s, o);
        const float inv = 1.f/s;
        #pragma unroll
        for (int j = 0; j < 8; ++j){
            float p = e8[j]*inv;
            ushort ph = f2bu(p);
            ahi[i][l + 64*j] = ph;
            alo_[i][l + 64*j] = f2bu(p - bu2f(ph));
        }
    }
    __syncthreads();

    f32x4 acc = {0.f,0.f,0.f,0.f};
    {
        const ushort* bhiP = H1Thi + ((size_t)b*HH + w*16 + c16)*NN + quad*8;
        const ushort* bloP = H1Tlo + ((size_t)b*HH + w*16 + c16)*NN + quad*8;
        const ushort* ahiP = &ahi[c16][quad*8];
        const ushort* aloP = &alo_[c16][quad*8];
        #pragma unroll
        for (int kk = 0; kk < 16; ++kk){
            short8 fa_hi = *(const short8*)(ahiP + kk*32);
            short8 fa_lo = *(const short8*)(aloP + kk*32);
            short8 fb_hi = *(const short8*)(bhiP + kk*32);
            short8 fb_lo = *(const short8*)(bloP + kk*32);
            acc = __builtin_amdgcn_mfma_f32_16x16x32_bf16(fa_hi, fb_hi, acc, 0,0,0);
            acc = __builtin_amdgcn_mfma_f32_16x16x32_bf16(fa_lo, fb_hi, acc, 0,0,0);
            acc = __builtin_amdgcn_mfma_f32_16x16x32_bf16(fa_hi, fb_lo, acc, 0,0,0);
        }
    }
    {
        const int h = w*16 + c16;
        const float bv = bias1[h];
        #pragma unroll
        for (int reg = 0; reg < 4; ++reg)
            xh2[quad*4 + reg][h] = gelu_exact(acc[reg] + bv);
    }
    __syncthreads();
    #pragma unroll
    for (int i = 0; i < 16; ++i) sw2[t + 256*i] = W2[t + 256*i];
    __syncthreads();
    {
        const int h = l;
        for (int q = 0; q < 4; ++q){
            const int i = w + 4*q;
            float acc2 = 0.f;
            const float4* xr = (const float4*)&xh2[i][0];
            #pragma unroll
            for (int k4 = 0; k4 < 16; ++k4){
                float4 xv = xr[k4];
                acc2 += xv.x*sw2[(4*k4+0)*HH+h] + xv.y*sw2[(4*k4+1)*HH+h]
                      + xv.z*sw2[(4*k4+2)*HH+h] + xv.w*sw2[(4*k4+3)*HH+h];
            }
            ushort vh = f2bu(acc2);
            th2[i][h] = vh;
            tl2[i][h] = f2bu(acc2 - bu2f(vh));
            float v1 = acc2*sal[h], v2 = acc2*sar[h];
            #pragma unroll
            for (int o = 32; o; o >>= 1){ v1 += __shfl_xor(v1,o); v2 += __shfl_xor(v2,o); }
            if (h == 0){ el2[b*NN + m0 + i] = v1; er2[b*NN + m0 + i] = v2; }
        }
    }
    __syncthreads();
    #pragma unroll
    for (int p = 0; p < 4; ++p){
        int hh2 = (t >> 4) + 16*p, n2 = t & 15;
        size_t og = ((size_t)b*HH + hh2)*NN + m0 + n2;
        H2Thi[og] = th2[n2][hh2];
        H2Tlo[og] = tl2[n2][hh2];
    }
}

// =============== K3: attn layer2 + LN(g2)+LN(hl) + decode (verified round 1) ===============
__global__ __launch_bounds__(256,2) void attn2_final_kernel(
    const ushort* __restrict__ H2Thi, const ushort* __restrict__ H2Tlo,
    const float* __restrict__ el_in, const float* __restrict__ er_in,
    const unsigned* __restrict__ maskG,
    const float* __restrict__ bias2,
    const float* __restrict__ hl,
    const float* __restrict__ g_l, const float* __restrict__ b_l,
    const float* __restrict__ g_g, const float* __restrict__ b_g,
    const float* __restrict__ W_d, const float* __restrict__ b_d,
    float* __restrict__ out)
{
    __shared__ __align__(16) char smem[40448];
    unsigned (*smask)[16] = (unsigned(*)[16])smem;                 // 1024
    float* er_s  = (float*)(smem + 1024);                          // 2048
    ushort (*ahi)[520] = (ushort(*)[520])(smem + 3072);            // -> 19712
    ushort (*alo_)[520] = (ushort(*)[520])(smem + 19712);          // -> 36352
    float* sg2  = (float*)(smem + 36352);                          // 4096 -> 40448
    float* sdec = (float*)(smem + 3072);                           // overlay alpha

    const int t = threadIdx.x;
    const int b = blockIdx.x >> 5;
    const int m0 = (blockIdx.x & 31) * 16;
    const int l = t & 63, w = t >> 6;
    const int quad = l >> 4, c16 = l & 15;

    ((unsigned*)smask)[t] = maskG[m0*16 + t];
    er_s[t] = er_in[b*NN + t];
    er_s[t+256] = er_in[b*NN + t + 256];
    __syncthreads();
    for (int q = 0; q < 4; ++q){
        const int i = w*4 + q;
        const float elv = el_in[b*NN + m0 + i];
        float e8[8]; unsigned mk = 0; float mx = -1e30f;
        #pragma unroll
        for (int j = 0; j < 8; ++j){
            int n = l + 64*j;
            float ev = elv + er_s[n];
            ev = ev >= 0.f ? ev : 0.2f*ev;
            unsigned mb = (smask[i][(l>>5) + 2*j] >> (l & 31)) & 1u;
            e8[j] = ev;
            if (mb){ mk |= (1u<<j); mx = fmaxf(mx, ev); }
        }
        #pragma unroll
        for (int o = 32; o; o >>= 1) mx = fmaxf(mx, __shfl_xor(mx, o));
        float s = 0.f;
        #pragma unroll
        for (int j = 0; j < 8; ++j){
            float p = ((mk>>j) & 1u) ? __expf(e8[j]-mx) : 0.f;
            e8[j] = p; s += p;
        }
        #pragma unroll
        for (int o = 32; o; o >>= 1) s += __shfl_xor(s, o);
        const float inv = 1.f/s;
        #pragma unroll
        for (int j = 0; j < 8; ++j){
            float p = e8[j]*inv;
            ushort ph = f2bu(p);
            ahi[i][l + 64*j] = ph;
            alo_[i][l + 64*j] = f2bu(p - bu2f(ph));
        }
    }
    __syncthreads();

    f32x4 acc = {0.f,0.f,0.f,0.f};
    {
        const ushort* bhiP = H2Thi + ((size_t)b*HH + w*16 + c16)*NN + quad*8;
        const ushort* bloP = H2Tlo + ((size_t)b*HH + w*16 + c16)*NN + quad*8;
        const ushort* ahiP = &ahi[c16][quad*8];
        const ushort* aloP = &alo_[c16][quad*8];
        #pragma unroll
        for (int kk = 0; kk < 16; ++kk){
            short8 fa_hi = *(const short8*)(ahiP + kk*32);
            short8 fa_lo = *(const short8*)(aloP + kk*32);
            short8 fb_hi = *(const short8*)(bhiP + kk*32);
            short8 fb_lo = *(const short8*)(bloP + kk*32);
            acc = __builtin_amdgcn_mfma_f32_16x16x32_bf16(fa_hi, fb_hi, acc, 0,0,0);
            acc = __builtin_amdgcn_mfma_f32_16x16x32_bf16(fa_lo, fb_hi, acc, 0,0,0);
            acc = __builtin_amdgcn_mfma_f32_16x16x32_bf16(fa_hi, fb_lo, acc, 0,0,0);
        }
    }
    {
        const int h = w*16 + c16;
        const float bv = bias2[h];
        #pragma unroll
        for (int reg = 0; reg < 4; ++reg)
            sg2[(quad*4 + reg)*HH + h] = gelu_exact(acc[reg] + bv);
    }
    __syncthreads();
    const int gbase = b*NN + m0;
    {
        const int h = l;
        for (int q = 0; q < 4; ++q){
            const int ml = w*4 + q;
            float gv = sg2[ml*HH + h];
            float lv = hl[(size_t)(gbase + ml)*HH + h];

            float s1 = gv;
            #pragma unroll
            for (int o = 32; o; o >>= 1) s1 += __shfl_xor(s1, o);
            float dg = gv - s1*(1.f/64.f);
            float v1 = dg*dg;
            #pragma unroll
            for (int o = 32; o; o >>= 1) v1 += __shfl_xor(v1, o);
            float lng = dg*rsqrtf(v1*(1.f/64.f) + 1e-5f)*g_g[h] + b_g[h];

            float s2 = lv;
            #pragma unroll
            for (int o = 32; o; o >>= 1) s2 += __shfl_xor(s2, o);
            float dl = lv - s2*(1.f/64.f);
            float v2 = dl*dl;
            #pragma unroll
            for (int o = 32; o; o >>= 1) v2 += __shfl_xor(v2, o);
            float lnl = dl*rsqrtf(v2*(1.f/64.f) + 1e-5f)*g_l[h] + b_l[h];

            sdec[ml*HH + h] = lng + lnl;
        }
    }
    __syncthreads();
    if (t < 16*PRED){
        int rr = t / PRED, pp = t - rr*PRED;
        float a = b_d[pp];
        #pragma unroll
        for (int k = 0; k < HH; ++k) a += sdec[rr*HH + k]*W_d[k*PRED + pp];
        out[(size_t)(gbase + rr)*PRED + pp] = a;
    }
}

extern "C" void kernel_launch(void* const* d_in, const int* in_sizes, int n_in,
                              void* d_out, int out_size, void* d_ws, size_t ws_size,
                              hipStream_t stream){
    const float* x    = (const float*)d_in[0];
    const int*   ei   = (const int*)  d_in[1];
    const float* Wfc  = (const float*)d_in[2];
    const float* bfc  = (const float*)d_in[3];
    const float* W1   = (const float*)d_in[4];
    const float* al1  = (const float*)d_in[5];
    const float* ar1  = (const float*)d_in[6];
    const float* bias1= (const float*)d_in[7];
    const float* W2   = (const float*)d_in[8];
    const float* al2  = (const float*)d_in[9];
    const float* ar2  = (const float*)d_in[10];
    const float* bias2= (const float*)d_in[11];
    const float* Wih  = (const float*)d_in[12];
    const float* Whh  = (const float*)d_in[13];
    const float* bih  = (const float*)d_in[14];
    const float* bhh  = (const float*)d_in[15];
    const float* g_l  = (const float*)d_in[16];
    const float* b_l  = (const float*)d_in[17];
    const float* g_g  = (const float*)d_in[18];
    const float* b_g  = (const float*)d_in[19];
    const float* W_d  = (const float*)d_in[20];
    const float* b_d  = (const float*)d_in[21];

    float* ws = (float*)d_ws;
    const int E = in_sizes[1] / 2;

    gat1pre_kernel<<<137, 256, 0, stream>>>(x, Wfc, bfc, W1, al1, ar1,
                                            Wih, Whh, bih, bhh, ei, E,
                                            (ushort*)(ws+WS_H1THI), (ushort*)(ws+WS_H1TLO),
                                            ws+WS_EL, ws+WS_ER,
                                            ws+WS_WCOMB, ws+WS_BCOMB,
                                            (ushort*)(ws+WS_WHHFRAG),
                                            (unsigned*)(ws+WS_MASK));
    mid_fused_kernel<<<256, 256, 0, stream>>>((const ushort*)(ws+WS_H1THI), (const ushort*)(ws+WS_H1TLO),
                                              ws+WS_EL, ws+WS_ER,
                                              (const unsigned*)(ws+WS_MASK),
                                              bias1, W2, al2, ar2,
                                              (ushort*)(ws+WS_H2THI), (ushort*)(ws+WS_H2TLO),
                                              ws+WS_EL2, ws+WS_ER2,
                                              x, ws+WS_WCOMB, ws+WS_BCOMB,
                                              (const ushort*)(ws+WS_WHHFRAG),
                                              ws+WS_HL);
    attn2_final_kernel<<<BB*(NN/16), 256, 0, stream>>>((const ushort*)(ws+WS_H2THI), (const ushort*)(ws+WS_H2TLO),
                                                       ws+WS_EL2, ws+WS_ER2,
                                                       (const unsigned*)(ws+WS_MASK),
                                                       bias2, ws+WS_HL,
                                                       g_l, b_l, g_g, b_g, W_d, b_d,
                                                       (float*)d_out);
}